// Round 18
// baseline (155.413 us; speedup 1.0000x reference)
//
#include <hip/hip_runtime.h>
#include <math.h>

#define NHEADS 4
#define HDIM   32
#define DMODEL 128
#define SLEN   8192
#define BATCH  8
#define QKVC   384   // 3 * NHEADS * HDIM

typedef __bf16 bf16x8 __attribute__((ext_vector_type(8)));
typedef float  f32x4  __attribute__((ext_vector_type(4)));

// round-to-nearest-even f32 -> bf16 bits
static __device__ __forceinline__ unsigned short f2bf(float f) {
    union { float f; unsigned int u; } v; v.f = f;
    unsigned int r = (v.u + 0x7FFFu + ((v.u >> 16) & 1u)) >> 16;
    return (unsigned short)r;
}
// hardware cvt pack (v_cvt_pk_bf16_f32)
static __device__ __forceinline__ unsigned int pk2(float a, float b) {
    unsigned short ua = __builtin_bit_cast(unsigned short, (__bf16)a);
    unsigned short ub = __builtin_bit_cast(unsigned short, (__bf16)b);
    return (unsigned int)ua | ((unsigned int)ub << 16);
}
static __device__ __forceinline__ float bf_lo(unsigned int u) {
    union { unsigned int u; float f; } v; v.u = u << 16; return v.f;
}
static __device__ __forceinline__ float bf_hi(unsigned int u) {
    union { unsigned int u; float f; } v; v.u = u & 0xffff0000u; return v.f;
}

// ---------------------------------------------------------------------------
// Kernel P: prep. blockIdx segments:
//   [0,64) : W_out f32[8192][128] -> Wt bf16 [128][8192] (transpose+cvt)
//   [64,88): W_qkv -> MFMA A-fragment buffer wfb (bf16, fragment order)
//   88     : zero the 32 per-mtile completion counters (graph-replay safe)
// ---------------------------------------------------------------------------
__global__ __launch_bounds__(256) void k_prep(
    const float* __restrict__ Wout, unsigned short* __restrict__ Wt,
    const float* __restrict__ Wqkv, unsigned short* __restrict__ wfb,
    unsigned int* __restrict__ cnt)
{
    const int tid = threadIdx.x;
    const int bx  = blockIdx.x;

    if (bx < 64) {
        __shared__ unsigned short ts[128][136];
        const float* src = Wout + (long)bx * 128 * 128;
        #pragma unroll
        for (int i = 0; i < 64; ++i) {
            const int idx = tid + i * 256;
            const int kk = idx >> 7, n = idx & 127;
            ts[n][kk] = f2bf(src[idx]);
        }
        __syncthreads();
        #pragma unroll
        for (int i = 0; i < 64; ++i) {
            const int idx = tid + i * 256;
            const int n = idx >> 7, kk = idx & 127;
            Wt[(long)n * SLEN + bx * 128 + kk] = ts[n][kk];
        }
    } else if (bx < 88) {
        const int idx  = (bx - 64) * 256 + tid;   // 0..6143
        const int lane = idx & 63;
        const int ks   = (idx >> 6) & 3;
        const int J    = idx >> 8;                // 0..23 channel tile
        const int ch   = J * 16 + (lane & 15);
        const int kb   = ks * 32 + (lane >> 4) * 8;
        unsigned short t[8];
        #pragma unroll
        for (int e = 0; e < 8; ++e) t[e] = f2bf(Wqkv[(kb + e) * QKVC + ch]);
        *(uint4*)(wfb + (long)idx * 8) = *(const uint4*)t;
    } else {
        if (tid < 32) cnt[tid] = 0u;
    }
}

// ---------------------------------------------------------------------------
// Kernel 1: fused QKV projection + per-position head-mixing attention.
// (R13 champion, byte-identical.) 512 blocks x 256 thr; FOUR 32-position
// tiles per block; double-buffered xs; early-issued prefetch; resident W
// fragments under __launch_bounds__(256,2). Do NOT raise the bounds arg or
// restructure register pressure: (256,3)/512-thr variants make the
// allocator spill the wf file to scratch (R14: 107 MB, R17: 185 MB).
// ---------------------------------------------------------------------------
__global__ __launch_bounds__(256, 2) void k_qkv_attn_mfma(
    const float* __restrict__ x,
    const unsigned short* __restrict__ wfb,
    const float* __restrict__ bqkv,
    unsigned short* __restrict__ attn_out)   // bf16 [65536][128]
{
    __shared__ unsigned short xs[2][32 * 136];  // double-buffered x tile bf16
    __shared__ unsigned short qsm[32 * 384];    // qkv bf16, chunk-swizzled rows

    const int tid  = threadIdx.x;
    const int lane = tid & 63;
    const int wave = tid >> 6;
    const int l16  = lane & 15;
    const int lhi  = lane >> 4;
    const long p00 = (long)blockIdx.x * 128;
    const int spos = tid >> 3;   // 0..31
    const int sseg = tid & 7;    // 0..7

    // ---- resident W fragments: 24 independent uint4 loads, batch-issued ----
    bf16x8 wf[6][4];
    {
        const unsigned short* wbase = wfb + ((long)(wave * 24) * 64 + lane) * 8;
        #pragma unroll
        for (int j = 0; j < 6; ++j)
            #pragma unroll
            for (int ks = 0; ks < 4; ++ks)
                wf[j][ks] = __builtin_bit_cast(bf16x8,
                    *(const uint4*)(wbase + (j * 4 + ks) * 512));
    }

    // stage a 32-pos tile from 4 float4 regs into xs[buf]
    auto stage_write = [&](int buf, float4 a0, float4 a1, float4 a2, float4 a3) {
        unsigned int t[8] = {
            pk2(a0.x, a0.y), pk2(a0.z, a0.w), pk2(a1.x, a1.y), pk2(a1.z, a1.w),
            pk2(a2.x, a2.y), pk2(a2.z, a2.w), pk2(a3.x, a3.y), pk2(a3.z, a3.w) };
        *(uint4*)(xs[buf] + spos * 136 + sseg * 16)     = ((const uint4*)t)[0];
        *(uint4*)(xs[buf] + spos * 136 + sseg * 16 + 8) = ((const uint4*)t)[1];
    };

    // MFMA phase: reads xs[buf] + resident wf, writes qsm (+bias)
    auto mfma_phase = [&](int buf) {
        f32x4 acc[6][2];
        #pragma unroll
        for (int j = 0; j < 6; ++j)
            #pragma unroll
            for (int nt = 0; nt < 2; ++nt) acc[j][nt] = (f32x4){0.f, 0.f, 0.f, 0.f};

        #pragma unroll
        for (int ks = 0; ks < 4; ++ks) {
            const bf16x8 xf0 = __builtin_bit_cast(bf16x8,
                *(const uint4*)(xs[buf] + l16 * 136 + ks * 32 + lhi * 8));
            const bf16x8 xf1 = __builtin_bit_cast(bf16x8,
                *(const uint4*)(xs[buf] + (16 + l16) * 136 + ks * 32 + lhi * 8));
            #pragma unroll
            for (int j = 0; j < 6; ++j) {
                acc[j][0] = __builtin_amdgcn_mfma_f32_16x16x32_bf16(wf[j][ks], xf0, acc[j][0], 0, 0, 0);
                acc[j][1] = __builtin_amdgcn_mfma_f32_16x16x32_bf16(wf[j][ks], xf1, acc[j][1], 0, 0, 0);
            }
        }
        #pragma unroll
        for (int j = 0; j < 6; ++j) {
            const float4 bb = *(const float4*)(bqkv + wave * 96 + j * 16 + lhi * 4);
            const int c     = wave * 96 + lhi * 4 + j * 16;
            const int chunk = c >> 3;
            const int sub   = c & 7;          // 0 or 4
            #pragma unroll
            for (int nt = 0; nt < 2; ++nt) {
                const int p = nt * 16 + l16;  // p & 15 == l16
                uint2 u;
                u.x = pk2(acc[j][nt][0] + bb.x, acc[j][nt][1] + bb.y);
                u.y = pk2(acc[j][nt][2] + bb.z, acc[j][nt][3] + bb.w);
                *(uint2*)(qsm + p * 384 + (((chunk ^ l16) << 3) + sub)) = u;
            }
        }
    };

    // epilogue: 256 threads = (p = tid>>3, qh = (tid>>1)&3, h = tid&1)
    auto epilogue = [&](long p0) {
        const int p   = tid >> 3;
        const int qh  = (tid >> 1) & 3;
        const int h   = tid & 1;
        const int psw = p & 15;
        const unsigned short* row = qsm + p * 384;
        const float scale = 0.17677669529663687f;   // 32^-0.5

        float qf[16];
        {
            const int qc = qh * 12 + h * 2;
            #pragma unroll
            for (int cc = 0; cc < 2; ++cc) {
                const uint4 qv = *(const uint4*)(row + (((qc + cc) ^ psw) << 3));
                const unsigned int* w = (const unsigned int*)&qv;
                #pragma unroll
                for (int k = 0; k < 4; ++k) {
                    qf[cc * 8 + 2 * k]     = bf_lo(w[k]);
                    qf[cc * 8 + 2 * k + 1] = bf_hi(w[k]);
                }
            }
        }
        float sc[NHEADS];
        #pragma unroll
        for (int kh = 0; kh < NHEADS; ++kh) {
            float s = 0.f;
            const int kc = kh * 12 + 4 + h * 2;
            #pragma unroll
            for (int cc = 0; cc < 2; ++cc) {
                const uint4 kv = *(const uint4*)(row + (((kc + cc) ^ psw) << 3));
                const unsigned int* w = (const unsigned int*)&kv;
                #pragma unroll
                for (int k = 0; k < 4; ++k) {
                    s = fmaf(bf_lo(w[k]), qf[cc * 8 + 2 * k], s);
                    s = fmaf(bf_hi(w[k]), qf[cc * 8 + 2 * k + 1], s);
                }
            }
            sc[kh] = (s + __shfl_xor(s, 1)) * scale;
        }
        const float m = fmaxf(fmaxf(sc[0], sc[1]), fmaxf(sc[2], sc[3]));
        float ew[NHEADS], sum = 0.f;
        #pragma unroll
        for (int kh = 0; kh < NHEADS; ++kh) { ew[kh] = __expf(sc[kh] - m); sum += ew[kh]; }
        const float inv = 1.f / sum;
        #pragma unroll
        for (int kh = 0; kh < NHEADS; ++kh) ew[kh] *= inv;

        float o[16];
        #pragma unroll
        for (int e = 0; e < 16; ++e) o[e] = 0.f;
        #pragma unroll
        for (int kh = 0; kh < NHEADS; ++kh) {
            const float wk = ew[kh];
            const int vc = kh * 12 + 8 + h * 2;
            #pragma unroll
            for (int cc = 0; cc < 2; ++cc) {
                const uint4 vv = *(const uint4*)(row + (((vc + cc) ^ psw) << 3));
                const unsigned int* w = (const unsigned int*)&vv;
                #pragma unroll
                for (int k = 0; k < 4; ++k) {
                    o[cc * 8 + 2 * k]     = fmaf(wk, bf_lo(w[k]), o[cc * 8 + 2 * k]);
                    o[cc * 8 + 2 * k + 1] = fmaf(wk, bf_hi(w[k]), o[cc * 8 + 2 * k + 1]);
                }
            }
        }
        unsigned int ow[8];
        #pragma unroll
        for (int e = 0; e < 8; ++e) ow[e] = pk2(o[2 * e], o[2 * e + 1]);
        unsigned short* dst = attn_out + (p0 + p) * DMODEL + qh * 32 + h * 16;
        *(uint4*)(dst)     = ((const uint4*)ow)[0];
        *(uint4*)(dst + 8) = ((const uint4*)ow)[1];
    };

    // ---- prologue: stage tile 0 into xs[0] ----
    {
        const float* src = x + (p00 + spos) * DMODEL + sseg * 16;
        stage_write(0, *(const float4*)(src),     *(const float4*)(src + 4),
                       *(const float4*)(src + 8), *(const float4*)(src + 12));
    }
    __syncthreads();                 // xs[0] ready

    for (int it = 0; it < 4; ++it) {
        const int cur = it & 1;

        // issue next-tile loads EARLY: covered by MFMA + barrier + epilogue
        float4 xv0, xv1, xv2, xv3;
        if (it < 3) {
            const float* src = x + (p00 + (it + 1) * 32 + spos) * DMODEL + sseg * 16;
            xv0 = *(const float4*)(src);      xv1 = *(const float4*)(src + 4);
            xv2 = *(const float4*)(src + 8);  xv3 = *(const float4*)(src + 12);
        }

        mfma_phase(cur);
        __syncthreads();             // qsm ready; xs[cur] consumed

        if (it < 3)
            stage_write(cur ^ 1, xv0, xv1, xv2, xv3);   // idle buffer, no race
        epilogue(p00 + it * 32);
        __syncthreads();             // qsm free; xs[cur^1] ready
    }
}

// ---------------------------------------------------------------------------
// Kernel 2: final GEMM partials via bf16 MFMA + last-block reduction.
//   C(1024x128) = Aflat(1024x8192 bf16) @ W(8192x128)
// Grid: 32 M-tiles (32 rows) x 16 K-chunks = 512 blocks (2 blocks/CU).
// Each block writes its P partial, threadfence + per-mtile counter; the
// 16th block of an mtile sums the 16 partials (fixed kc order -> fully
// deterministic) via volatile (sc0, L1-bypassing) loads, adds bias, writes
// out. Replaces the separate k_reduce launch.
// ---------------------------------------------------------------------------
__global__ __launch_bounds__(256, 2) void k_fgemm_mfma(
    const unsigned short* __restrict__ attnBf,   // [1024][8192] bf16 (flat view)
    const unsigned short* __restrict__ WtBf,     // [128][8192] bf16
    float* __restrict__ P,                       // [16][1024][128] f32 partials
    unsigned int* __restrict__ cnt,              // [32] per-mtile counters
    const float* __restrict__ bout,
    float* __restrict__ out)                     // [1024][128] f32
{
    __shared__ unsigned short As[32][136];
    __shared__ unsigned short Ws[128][136];
    __shared__ bool isLast;

    const int tid   = threadIdx.x;
    const int mtile = blockIdx.x >> 4;     // 0..31
    const int kc    = blockIdx.x & 15;     // 0..15
    const int lane  = tid & 63;
    const int wave  = tid >> 6;
    const int l16   = lane & 15;
    const int lhi   = lane >> 4;

    f32x4 acc[2][2];
    #pragma unroll
    for (int mf = 0; mf < 2; ++mf)
        #pragma unroll
        for (int nt = 0; nt < 2; ++nt) acc[mf][nt] = (f32x4){0.f, 0.f, 0.f, 0.f};

    for (int st = 0; st < 4; ++st) {
        const int k0 = kc * 512 + st * 128;
        __syncthreads();
        #pragma unroll
        for (int i = 0; i < 2; ++i) {
            const int c = tid + i * 256;
            const int m = c >> 4, k8 = c & 15;
            const uint4 v = *(const uint4*)(attnBf + (long)(mtile * 32 + m) * SLEN + k0 + k8 * 8);
            *(uint4*)(&As[m][k8 * 8]) = v;
        }
        #pragma unroll
        for (int i = 0; i < 8; ++i) {
            const int c = tid + i * 256;
            const int n = c >> 4, k8 = c & 15;
            const uint4 v = *(const uint4*)(WtBf + (long)n * SLEN + k0 + k8 * 8);
            *(uint4*)(&Ws[n][k8 * 8]) = v;
        }
        __syncthreads();

        #pragma unroll
        for (int ks = 0; ks < 4; ++ks) {
            const int kk = ks * 32 + lhi * 8;
            bf16x8 af[2], bfr[2];
            #pragma unroll
            for (int mf = 0; mf < 2; ++mf)
                af[mf] = __builtin_bit_cast(bf16x8, *(const uint4*)(&As[mf * 16 + l16][kk]));
            #pragma unroll
            for (int nt = 0; nt < 2; ++nt)
                bfr[nt] = __builtin_bit_cast(bf16x8, *(const uint4*)(&Ws[(wave * 2 + nt) * 16 + l16][kk]));
            #pragma unroll
            for (int mf = 0; mf < 2; ++mf)
                #pragma unroll
                for (int nt = 0; nt < 2; ++nt)
                    acc[mf][nt] = __builtin_amdgcn_mfma_f32_16x16x32_bf16(af[mf], bfr[nt], acc[mf][nt], 0, 0, 0);
        }
    }

    const long base = (long)(mtile * 32) * 128;
    float* Pp = P + (long)kc * 131072 + base;
    #pragma unroll
    for (int mf = 0; mf < 2; ++mf) {
        #pragma unroll
        for (int nt = 0; nt < 2; ++nt) {
            const int n = (wave * 2 + nt) * 16 + l16;
            #pragma unroll
            for (int r = 0; r < 4; ++r) {
                const int m = mf * 16 + lhi * 4 + r;
                Pp[m * 128 + n] = acc[mf][nt][r];
            }
        }
    }

    // ---- last-block reduction (replaces k_reduce) ----
    __threadfence();                           // make P writes device-visible
    if (tid == 0)
        isLast = (atomicAdd(&cnt[mtile], 1u) == 15u);
    __syncthreads();
    if (isLast) {
        const volatile float* Pv = P;          // sc0 loads: bypass stale L1
        #pragma unroll
        for (int i = 0; i < 16; ++i) {
            const int idx = tid + i * 256;     // 0..4095
            float v = bout[idx & 127];
            #pragma unroll
            for (int kcc = 0; kcc < 16; ++kcc)
                v += Pv[(long)kcc * 131072 + base + idx];
            out[base + idx] = v;
        }
    }
}

// ---------------------------------------------------------------------------
extern "C" void kernel_launch(void* const* d_in, const int* in_sizes, int n_in,
                              void* d_out, int out_size, void* d_ws, size_t ws_size,
                              hipStream_t stream)
{
    const float* x    = (const float*)d_in[0];
    const float* Wqkv = (const float*)d_in[1];
    const float* bqkv = (const float*)d_in[2];
    const float* Wout = (const float*)d_in[3];
    const float* bout = (const float*)d_in[4];
    float* out = (float*)d_out;

    // ws: [0,16M) attn bf16 | [16,18M) Wt bf16 | [18,26M) P f32 | [26M) wfb
    //     [27M) counters
    unsigned short* attnBf = (unsigned short*)d_ws;
    unsigned short* WtBf   = (unsigned short*)((char*)d_ws + (16u << 20));
    float*          P      = (float*)((char*)d_ws + (18u << 20));
    unsigned short* wfb    = (unsigned short*)((char*)d_ws + (26u << 20));
    unsigned int*   cnt    = (unsigned int*)((char*)d_ws + (27u << 20));

    k_prep<<<89, 256, 0, stream>>>(Wout, WtBf, Wqkv, wfb, cnt);
    k_qkv_attn_mfma<<<512, 256, 0, stream>>>(x, wfb, bqkv, attnBf);
    k_fgemm_mfma<<<512, 256, 0, stream>>>(attnBf, WtBf, P, cnt, bout, out);
}

// Round 19
// 38.607 us; speedup vs baseline: 4.0255x; 4.0255x over previous
//
#include <hip/hip_runtime.h>
#include <math.h>

#define NHEADS 4
#define HDIM   32
#define DMODEL 128
#define SLEN   8192
#define BATCH  8
#define QKVC   384   // 3 * NHEADS * HDIM

typedef __bf16 bf16x8 __attribute__((ext_vector_type(8)));
typedef float  f32x4  __attribute__((ext_vector_type(4)));

// round-to-nearest-even f32 -> bf16 bits
static __device__ __forceinline__ unsigned short f2bf(float f) {
    union { float f; unsigned int u; } v; v.f = f;
    unsigned int r = (v.u + 0x7FFFu + ((v.u >> 16) & 1u)) >> 16;
    return (unsigned short)r;
}
// hardware cvt pack (v_cvt_pk_bf16_f32)
static __device__ __forceinline__ unsigned int pk2(float a, float b) {
    unsigned short ua = __builtin_bit_cast(unsigned short, (__bf16)a);
    unsigned short ub = __builtin_bit_cast(unsigned short, (__bf16)b);
    return (unsigned int)ua | ((unsigned int)ub << 16);
}
static __device__ __forceinline__ float bf_lo(unsigned int u) {
    union { unsigned int u; float f; } v; v.u = u << 16; return v.f;
}
static __device__ __forceinline__ float bf_hi(unsigned int u) {
    union { unsigned int u; float f; } v; v.u = u & 0xffff0000u; return v.f;
}

// ---------------------------------------------------------------------------
// Kernel P: prep. blockIdx segments:
//   [0,64) : W_out f32[8192][128] -> Wt bf16 [128][8192] (transpose+cvt)
//   [64,88): W_qkv -> MFMA A-fragment buffer wfb (bf16, fragment order)
// ---------------------------------------------------------------------------
__global__ __launch_bounds__(256) void k_prep(
    const float* __restrict__ Wout, unsigned short* __restrict__ Wt,
    const float* __restrict__ Wqkv, unsigned short* __restrict__ wfb)
{
    const int tid = threadIdx.x;
    const int bx  = blockIdx.x;

    if (bx < 64) {
        __shared__ unsigned short ts[128][136];
        const float* src = Wout + (long)bx * 128 * 128;
        #pragma unroll
        for (int i = 0; i < 64; ++i) {
            const int idx = tid + i * 256;
            const int kk = idx >> 7, n = idx & 127;
            ts[n][kk] = f2bf(src[idx]);
        }
        __syncthreads();
        #pragma unroll
        for (int i = 0; i < 64; ++i) {
            const int idx = tid + i * 256;
            const int n = idx >> 7, kk = idx & 127;
            Wt[(long)n * SLEN + bx * 128 + kk] = ts[n][kk];
        }
    } else {
        const int idx  = (bx - 64) * 256 + tid;   // 0..6143
        const int lane = idx & 63;
        const int ks   = (idx >> 6) & 3;
        const int J    = idx >> 8;                // 0..23 channel tile
        const int ch   = J * 16 + (lane & 15);
        const int kb   = ks * 32 + (lane >> 4) * 8;
        unsigned short t[8];
        #pragma unroll
        for (int e = 0; e < 8; ++e) t[e] = f2bf(Wqkv[(kb + e) * QKVC + ch]);
        *(uint4*)(wfb + (long)idx * 8) = *(const uint4*)t;
    }
}

// ---------------------------------------------------------------------------
// Kernel 1: fused QKV projection + per-position head-mixing attention.
// (R13 champion.) 512 blocks x 256 thr; FOUR 32-position tiles per block;
// double-buffered xs; early-issued prefetch; resident W fragments under
// __launch_bounds__(256,2). Do NOT raise the bounds arg, widen the block,
// or add volatile/atomic epilogues: every such variant (R14/R15/R17/R18)
// made the allocator spill or deoptimize (scratch traffic, 2-4x slower).
// ---------------------------------------------------------------------------
__global__ __launch_bounds__(256, 2) void k_qkv_attn_mfma(
    const float* __restrict__ x,
    const unsigned short* __restrict__ wfb,
    const float* __restrict__ bqkv,
    unsigned short* __restrict__ attn_out)   // bf16 [65536][128]
{
    __shared__ unsigned short xs[2][32 * 136];  // double-buffered x tile bf16
    __shared__ unsigned short qsm[32 * 384];    // qkv bf16, chunk-swizzled rows

    const int tid  = threadIdx.x;
    const int lane = tid & 63;
    const int wave = tid >> 6;
    const int l16  = lane & 15;
    const int lhi  = lane >> 4;
    const long p00 = (long)blockIdx.x * 128;
    const int spos = tid >> 3;   // 0..31
    const int sseg = tid & 7;    // 0..7

    // ---- resident W fragments: 24 independent uint4 loads, batch-issued ----
    bf16x8 wf[6][4];
    {
        const unsigned short* wbase = wfb + ((long)(wave * 24) * 64 + lane) * 8;
        #pragma unroll
        for (int j = 0; j < 6; ++j)
            #pragma unroll
            for (int ks = 0; ks < 4; ++ks)
                wf[j][ks] = __builtin_bit_cast(bf16x8,
                    *(const uint4*)(wbase + (j * 4 + ks) * 512));
    }

    // stage a 32-pos tile from 4 float4 regs into xs[buf]
    auto stage_write = [&](int buf, float4 a0, float4 a1, float4 a2, float4 a3) {
        unsigned int t[8] = {
            pk2(a0.x, a0.y), pk2(a0.z, a0.w), pk2(a1.x, a1.y), pk2(a1.z, a1.w),
            pk2(a2.x, a2.y), pk2(a2.z, a2.w), pk2(a3.x, a3.y), pk2(a3.z, a3.w) };
        *(uint4*)(xs[buf] + spos * 136 + sseg * 16)     = ((const uint4*)t)[0];
        *(uint4*)(xs[buf] + spos * 136 + sseg * 16 + 8) = ((const uint4*)t)[1];
    };

    // MFMA phase: reads xs[buf] + resident wf, writes qsm (+bias)
    auto mfma_phase = [&](int buf) {
        f32x4 acc[6][2];
        #pragma unroll
        for (int j = 0; j < 6; ++j)
            #pragma unroll
            for (int nt = 0; nt < 2; ++nt) acc[j][nt] = (f32x4){0.f, 0.f, 0.f, 0.f};

        #pragma unroll
        for (int ks = 0; ks < 4; ++ks) {
            const bf16x8 xf0 = __builtin_bit_cast(bf16x8,
                *(const uint4*)(xs[buf] + l16 * 136 + ks * 32 + lhi * 8));
            const bf16x8 xf1 = __builtin_bit_cast(bf16x8,
                *(const uint4*)(xs[buf] + (16 + l16) * 136 + ks * 32 + lhi * 8));
            #pragma unroll
            for (int j = 0; j < 6; ++j) {
                acc[j][0] = __builtin_amdgcn_mfma_f32_16x16x32_bf16(wf[j][ks], xf0, acc[j][0], 0, 0, 0);
                acc[j][1] = __builtin_amdgcn_mfma_f32_16x16x32_bf16(wf[j][ks], xf1, acc[j][1], 0, 0, 0);
            }
        }
        #pragma unroll
        for (int j = 0; j < 6; ++j) {
            const float4 bb = *(const float4*)(bqkv + wave * 96 + j * 16 + lhi * 4);
            const int c     = wave * 96 + lhi * 4 + j * 16;
            const int chunk = c >> 3;
            const int sub   = c & 7;          // 0 or 4
            #pragma unroll
            for (int nt = 0; nt < 2; ++nt) {
                const int p = nt * 16 + l16;  // p & 15 == l16
                uint2 u;
                u.x = pk2(acc[j][nt][0] + bb.x, acc[j][nt][1] + bb.y);
                u.y = pk2(acc[j][nt][2] + bb.z, acc[j][nt][3] + bb.w);
                *(uint2*)(qsm + p * 384 + (((chunk ^ l16) << 3) + sub)) = u;
            }
        }
    };

    // epilogue: 256 threads = (p = tid>>3, qh = (tid>>1)&3, h = tid&1)
    auto epilogue = [&](long p0) {
        const int p   = tid >> 3;
        const int qh  = (tid >> 1) & 3;
        const int h   = tid & 1;
        const int psw = p & 15;
        const unsigned short* row = qsm + p * 384;
        const float scale = 0.17677669529663687f;   // 32^-0.5

        float qf[16];
        {
            const int qc = qh * 12 + h * 2;
            #pragma unroll
            for (int cc = 0; cc < 2; ++cc) {
                const uint4 qv = *(const uint4*)(row + (((qc + cc) ^ psw) << 3));
                const unsigned int* w = (const unsigned int*)&qv;
                #pragma unroll
                for (int k = 0; k < 4; ++k) {
                    qf[cc * 8 + 2 * k]     = bf_lo(w[k]);
                    qf[cc * 8 + 2 * k + 1] = bf_hi(w[k]);
                }
            }
        }
        float sc[NHEADS];
        #pragma unroll
        for (int kh = 0; kh < NHEADS; ++kh) {
            float s = 0.f;
            const int kc = kh * 12 + 4 + h * 2;
            #pragma unroll
            for (int cc = 0; cc < 2; ++cc) {
                const uint4 kv = *(const uint4*)(row + (((kc + cc) ^ psw) << 3));
                const unsigned int* w = (const unsigned int*)&kv;
                #pragma unroll
                for (int k = 0; k < 4; ++k) {
                    s = fmaf(bf_lo(w[k]), qf[cc * 8 + 2 * k], s);
                    s = fmaf(bf_hi(w[k]), qf[cc * 8 + 2 * k + 1], s);
                }
            }
            sc[kh] = (s + __shfl_xor(s, 1)) * scale;
        }
        const float m = fmaxf(fmaxf(sc[0], sc[1]), fmaxf(sc[2], sc[3]));
        float ew[NHEADS], sum = 0.f;
        #pragma unroll
        for (int kh = 0; kh < NHEADS; ++kh) { ew[kh] = __expf(sc[kh] - m); sum += ew[kh]; }
        const float inv = 1.f / sum;
        #pragma unroll
        for (int kh = 0; kh < NHEADS; ++kh) ew[kh] *= inv;

        float o[16];
        #pragma unroll
        for (int e = 0; e < 16; ++e) o[e] = 0.f;
        #pragma unroll
        for (int kh = 0; kh < NHEADS; ++kh) {
            const float wk = ew[kh];
            const int vc = kh * 12 + 8 + h * 2;
            #pragma unroll
            for (int cc = 0; cc < 2; ++cc) {
                const uint4 vv = *(const uint4*)(row + (((vc + cc) ^ psw) << 3));
                const unsigned int* w = (const unsigned int*)&vv;
                #pragma unroll
                for (int k = 0; k < 4; ++k) {
                    o[cc * 8 + 2 * k]     = fmaf(wk, bf_lo(w[k]), o[cc * 8 + 2 * k]);
                    o[cc * 8 + 2 * k + 1] = fmaf(wk, bf_hi(w[k]), o[cc * 8 + 2 * k + 1]);
                }
            }
        }
        unsigned int ow[8];
        #pragma unroll
        for (int e = 0; e < 8; ++e) ow[e] = pk2(o[2 * e], o[2 * e + 1]);
        unsigned short* dst = attn_out + (p0 + p) * DMODEL + qh * 32 + h * 16;
        *(uint4*)(dst)     = ((const uint4*)ow)[0];
        *(uint4*)(dst + 8) = ((const uint4*)ow)[1];
    };

    // ---- prologue: stage tile 0 into xs[0] ----
    {
        const float* src = x + (p00 + spos) * DMODEL + sseg * 16;
        stage_write(0, *(const float4*)(src),     *(const float4*)(src + 4),
                       *(const float4*)(src + 8), *(const float4*)(src + 12));
    }
    __syncthreads();                 // xs[0] ready

    for (int it = 0; it < 4; ++it) {
        const int cur = it & 1;

        // issue next-tile loads EARLY: covered by MFMA + barrier + epilogue
        float4 xv0, xv1, xv2, xv3;
        if (it < 3) {
            const float* src = x + (p00 + (it + 1) * 32 + spos) * DMODEL + sseg * 16;
            xv0 = *(const float4*)(src);      xv1 = *(const float4*)(src + 4);
            xv2 = *(const float4*)(src + 8);  xv3 = *(const float4*)(src + 12);
        }

        mfma_phase(cur);
        __syncthreads();             // qsm ready; xs[cur] consumed

        if (it < 3)
            stage_write(cur ^ 1, xv0, xv1, xv2, xv3);   // idle buffer, no race
        epilogue(p00 + it * 32);
        __syncthreads();             // qsm free; xs[cur^1] ready
    }
}

// ---------------------------------------------------------------------------
// Kernel 2: final GEMM partials via bf16 MFMA.
//   C(1024x128) = Aflat(1024x8192 bf16) @ W(8192x128)
// Grid: 32 M-tiles (32 rows) x 16 K-chunks = 512 blocks (2 blocks/CU).
// ---------------------------------------------------------------------------
__global__ __launch_bounds__(256, 2) void k_fgemm_mfma(
    const unsigned short* __restrict__ attnBf,   // [1024][8192] bf16 (flat view)
    const unsigned short* __restrict__ WtBf,     // [128][8192] bf16
    float* __restrict__ P)                       // [16][1024][128] f32 partials
{
    __shared__ unsigned short As[32][136];
    __shared__ unsigned short Ws[128][136];

    const int tid   = threadIdx.x;
    const int mtile = blockIdx.x >> 4;     // 0..31
    const int kc    = blockIdx.x & 15;     // 0..15
    const int lane  = tid & 63;
    const int wave  = tid >> 6;
    const int l16   = lane & 15;
    const int lhi   = lane >> 4;

    f32x4 acc[2][2];
    #pragma unroll
    for (int mf = 0; mf < 2; ++mf)
        #pragma unroll
        for (int nt = 0; nt < 2; ++nt) acc[mf][nt] = (f32x4){0.f, 0.f, 0.f, 0.f};

    for (int st = 0; st < 4; ++st) {
        const int k0 = kc * 512 + st * 128;
        __syncthreads();
        #pragma unroll
        for (int i = 0; i < 2; ++i) {
            const int c = tid + i * 256;
            const int m = c >> 4, k8 = c & 15;
            const uint4 v = *(const uint4*)(attnBf + (long)(mtile * 32 + m) * SLEN + k0 + k8 * 8);
            *(uint4*)(&As[m][k8 * 8]) = v;
        }
        #pragma unroll
        for (int i = 0; i < 8; ++i) {
            const int c = tid + i * 256;
            const int n = c >> 4, k8 = c & 15;
            const uint4 v = *(const uint4*)(WtBf + (long)n * SLEN + k0 + k8 * 8);
            *(uint4*)(&Ws[n][k8 * 8]) = v;
        }
        __syncthreads();

        #pragma unroll
        for (int ks = 0; ks < 4; ++ks) {
            const int kk = ks * 32 + lhi * 8;
            bf16x8 af[2], bfr[2];
            #pragma unroll
            for (int mf = 0; mf < 2; ++mf)
                af[mf] = __builtin_bit_cast(bf16x8, *(const uint4*)(&As[mf * 16 + l16][kk]));
            #pragma unroll
            for (int nt = 0; nt < 2; ++nt)
                bfr[nt] = __builtin_bit_cast(bf16x8, *(const uint4*)(&Ws[(wave * 2 + nt) * 16 + l16][kk]));
            #pragma unroll
            for (int mf = 0; mf < 2; ++mf)
                #pragma unroll
                for (int nt = 0; nt < 2; ++nt)
                    acc[mf][nt] = __builtin_amdgcn_mfma_f32_16x16x32_bf16(af[mf], bfr[nt], acc[mf][nt], 0, 0, 0);
        }
    }

    float* Pp = P + ((long)kc * 1024 + mtile * 32) * 128;
    #pragma unroll
    for (int mf = 0; mf < 2; ++mf) {
        #pragma unroll
        for (int nt = 0; nt < 2; ++nt) {
            const int n = (wave * 2 + nt) * 16 + l16;
            #pragma unroll
            for (int r = 0; r < 4; ++r) {
                const int m = mf * 16 + lhi * 4 + r;
                Pp[m * 128 + n] = acc[mf][nt][r];
            }
        }
    }
}

// ---------------------------------------------------------------------------
// Kernel 3: reduce 16 K-chunk partials + bias -> out (also clears poison).
// ---------------------------------------------------------------------------
__global__ __launch_bounds__(256) void k_reduce(
    const float* __restrict__ P, const float* __restrict__ bout,
    float* __restrict__ out)
{
    const int idx = blockIdx.x * 256 + threadIdx.x;
    float v = bout[idx & 127];
    #pragma unroll
    for (int kcc = 0; kcc < 16; ++kcc) v += P[(long)kcc * 131072 + idx];
    out[idx] = v;
}

// ---------------------------------------------------------------------------
extern "C" void kernel_launch(void* const* d_in, const int* in_sizes, int n_in,
                              void* d_out, int out_size, void* d_ws, size_t ws_size,
                              hipStream_t stream)
{
    const float* x    = (const float*)d_in[0];
    const float* Wqkv = (const float*)d_in[1];
    const float* bqkv = (const float*)d_in[2];
    const float* Wout = (const float*)d_in[3];
    const float* bout = (const float*)d_in[4];
    float* out = (float*)d_out;

    // ws: [0,16M) attn bf16 | [16,18M) Wt bf16 | [18,26M) P f32 | [26M..) wfb
    unsigned short* attnBf = (unsigned short*)d_ws;
    unsigned short* WtBf   = (unsigned short*)((char*)d_ws + (16u << 20));
    float*          P      = (float*)((char*)d_ws + (18u << 20));
    unsigned short* wfb    = (unsigned short*)((char*)d_ws + (26u << 20));

    k_prep<<<88, 256, 0, stream>>>(Wout, WtBf, Wqkv, wfb);
    k_qkv_attn_mfma<<<512, 256, 0, stream>>>(x, wfb, bqkv, attnBf);
    k_fgemm_mfma<<<512, 256, 0, stream>>>(attnBf, WtBf, P);
    k_reduce<<<512, 256, 0, stream>>>(P, bout, out);
}